// Round 6
// baseline (538.397 us; speedup 1.0000x reference)
//
#include <hip/hip_runtime.h>
#include <hip/hip_bf16.h>

#define BATCH 8
#define CHN 256
#define HWN 16384
#define EPSV 1e-6f
#define ESCH 32

typedef __attribute__((ext_vector_type(8))) short bf16x8;
typedef __attribute__((ext_vector_type(4))) short s16x4;
typedef __attribute__((ext_vector_type(4))) float f32x4;
typedef __hip_bfloat16 bf16;

__device__ __forceinline__ short f2s(float f){
  union { bf16 h; short s; } u; u.h = __float2bfloat16(f); return u.s;
}
__device__ __forceinline__ void gload16(const bf16* g, bf16* l){
  __builtin_amdgcn_global_load_lds((const __attribute__((address_space(1))) void*)g,
                                   (__attribute__((address_space(3))) void*)l, 16, 0, 0);
}

// ---- K1: read x once: GN partial stats + raw transpose x^T -> bf16 ----------
__global__ __launch_bounds__(256) void xstats_t(const float* __restrict__ x,
    bf16* __restrict__ xt, float* __restrict__ pst){
  int b = blockIdx.y, n0 = blockIdx.x * 64;
  __shared__ bf16 tile[256][70];
  __shared__ float sg[32], ssg[32];
  int t = threadIdx.x;
  if (t < 32){ sg[t] = 0.f; ssg[t] = 0.f; }
  __syncthreads();
  const float* xb = x + (size_t)b * CHN * HWN;
  #pragma unroll 4
  for (int i = 0; i < 16; i++){
    int c = i * 16 + (t >> 4);
    int nf = (t & 15) * 4;
    float4 v = *(const float4*)(xb + (size_t)c * HWN + n0 + nf);
    tile[c][nf + 0] = __float2bfloat16(v.x);
    tile[c][nf + 1] = __float2bfloat16(v.y);
    tile[c][nf + 2] = __float2bfloat16(v.z);
    tile[c][nf + 3] = __float2bfloat16(v.w);
    float s  = v.x + v.y + v.z + v.w;
    float ss = v.x*v.x + v.y*v.y + v.z*v.z + v.w*v.w;
    s  += __shfl_xor(s, 1);  s  += __shfl_xor(s, 2);
    s  += __shfl_xor(s, 4);  s  += __shfl_xor(s, 8);
    ss += __shfl_xor(ss, 1); ss += __shfl_xor(ss, 2);
    ss += __shfl_xor(ss, 4); ss += __shfl_xor(ss, 8);
    if ((t & 15) == 0){ atomicAdd(&sg[c >> 3], s); atomicAdd(&ssg[c >> 3], ss); }
  }
  __syncthreads();
  bf16* o = xt + (size_t)b * HWN * CHN;
  #pragma unroll 4
  for (int j = 0; j < 64; j++)
    o[(size_t)(n0 + j) * CHN + t] = tile[t][j];
  if (t < 32){
    atomicAdd(&pst[(b * 32 + t) * 2],     sg[t]);
    atomicAdd(&pst[(b * 32 + t) * 2 + 1], ssg[t]);
  }
}

// ---- K2: per-batch folded weights W'[b] = W.diag(a_b) bf16; V shift vec -----
__global__ __launch_bounds__(256) void wprep(const float* __restrict__ Wq,
    const float* __restrict__ Wk, const float* __restrict__ Wv,
    const float* __restrict__ gamma, const float* __restrict__ beta,
    const float* __restrict__ bv, const float* __restrict__ pst,
    bf16* __restrict__ wbp, float* __restrict__ tvb){
  int w = blockIdx.x, b = blockIdx.y, t = threadIdx.x;
  const float* W = (w == 0) ? Wq : ((w == 1) ? Wk : Wv);
  __shared__ float a_s[256], sh_s[256], tj[4][256];
  {
    int bg = b * 32 + (t >> 3);
    float m   = pst[bg * 2] * (1.f / 131072.f);
    float var = pst[bg * 2 + 1] * (1.f / 131072.f) - m * m;
    float r = rsqrtf(var + EPSV);
    float a = r * gamma[t];
    a_s[t] = a;
    sh_s[t] = beta[t] - m * a;
  }
  __syncthreads();
  float mya = a_s[t], mysh = sh_s[t];
  int wv64 = t >> 6, lane = t & 63;
  bf16* wo = wbp + ((size_t)(w * 8 + b) << 16);
  for (int j = 0; j < 256; j++){
    float wv_ = W[j * 256 + t];
    wo[j * 256 + t] = __float2bfloat16(wv_ * mya);
    if (w == 2){
      float p = wv_ * mysh;
      p += __shfl_xor(p, 1);  p += __shfl_xor(p, 2);  p += __shfl_xor(p, 4);
      p += __shfl_xor(p, 8);  p += __shfl_xor(p, 16); p += __shfl_xor(p, 32);
      if (lane == 0) tj[wv64][j] = p;
    }
  }
  if (w == 2){
    __syncthreads();
    tvb[b * 256 + t] = tj[0][t] + tj[1][t] + tj[2][t] + tj[3][t] + bv[t];
  }
}

// ---- K3: weights-resident QKV projection ------------------------------------
// LDS: full W' chunk 256x256 (128 KB, staged once) + xt tile 64x256 (32 KB).
// ISV=0: grid(ns,b,ws 0..1): E=exp(W'x) -> Eout rows ws*2048+b*256+.., col-sums.
// ISV=1: grid(ns,b,1):       V^T[b][n][d] = W'v x + tvb.
template<int ISV>
__global__ __launch_bounds__(256, 1) void qkv_gemm(const bf16* __restrict__ wbp,
    const bf16* __restrict__ xt, const float* __restrict__ tvb,
    bf16* __restrict__ Eout, bf16* __restrict__ vt, float* __restrict__ sums){
  __shared__ bf16 lW[256 * 256];             // 128 KB
  __shared__ bf16 lX[64 * 256];              // 32 KB
  int t = threadIdx.x, ns = blockIdx.x, b = blockIdx.y, ws = blockIdx.z;
  int wsel = ISV ? 2 : ws;
  const bf16* Wsrc = wbp + ((size_t)(wsel * 8 + b) << 16);
  const bf16* Xb = xt + (size_t)b * HWN * CHN + (size_t)(ns * 512) * CHN;
  int lane = t & 63, w = t >> 6, r = lane & 15, kc = lane >> 4;
  int key_r = (r >> 1) & 3;

  // stage W' once (swizzled source -> linear LDS dest)
  #pragma unroll
  for (int rep = 0; rep < 32; rep++){
    int c = t + rep * 256; int row = c >> 5, q = c & 31;
    int kb = q >> 2, key = (row >> 1) & 3;
    gload16(Wsrc + row * 256 + kb * 32 + (((q & 3) ^ key) << 3), &lW[c * 8]);
  }
  // stage first xt tile
  #pragma unroll
  for (int rep = 0; rep < 8; rep++){
    int c = t + rep * 256; int row = c >> 5, q = c & 31;
    int kb = q >> 2, key = (row >> 1) & 3;
    gload16(Xb + (size_t)row * 256 + kb * 32 + (((q & 3) ^ key) << 3), &lX[c * 8]);
  }
  __syncthreads();

  const bf16* Ab = ISV ? &lW[(w * 64) * 256] : &lX[0];
  const bf16* Bb = ISV ? &lX[0] : &lW[(w * 64) * 256];
  float colp[4] = {0.f, 0.f, 0.f, 0.f};

  for (int it = 0; it < 8; it++){
    // T14: prefetch next tile to regs (hides under k-loop + epilogue)
    int4 pf[8];
    if (it < 7){
      const bf16* Xn = Xb + (size_t)((it + 1) * 64) * CHN;
      #pragma unroll
      for (int rep = 0; rep < 8; rep++){
        int c = t + rep * 256; int row = c >> 5, q = c & 31;
        int kb = q >> 2, key = (row >> 1) & 3;
        pf[rep] = *(const int4*)(Xn + (size_t)row * 256 + kb * 32 + (((q & 3) ^ key) << 3));
      }
    }
    f32x4 acc[4][4] = {};
    #pragma unroll
    for (int ks = 0; ks < 8; ks++){
      bf16x8 af[4], bfv[4];
      int slot = ks * 32 + ((kc ^ key_r) << 3);
      #pragma unroll
      for (int i = 0; i < 4; i++){
        af[i]  = *(const bf16x8*)&Ab[(i * 16 + r) * 256 + slot];
        bfv[i] = *(const bf16x8*)&Bb[(i * 16 + r) * 256 + slot];
      }
      #pragma unroll
      for (int i = 0; i < 4; i++)
        #pragma unroll
        for (int f = 0; f < 4; f++)
          acc[i][f] = __builtin_amdgcn_mfma_f32_16x16x32_bf16(af[i], bfv[f], acc[i][f], 0, 0, 0);
    }

    // epilogue (registers -> global; D row = A-side, col = B-side)
    if (!ISV){
      // row = n (i*16+kc*4+j), col = wrow (f*16+r)
      int ncol0 = ns * 512 + it * 64;
      #pragma unroll
      for (int f = 0; f < 4; f++){
        size_t rowg = (size_t)(ws * 2048 + b * 256 + w * 64 + f * 16 + r);
        #pragma unroll
        for (int i = 0; i < 4; i++){
          s16x4 pk;
          #pragma unroll
          for (int j = 0; j < 4; j++){
            float e = __expf(acc[i][f][j]);  // |q| small: no max-sub needed
            colp[f] += e;
            pk[j] = f2s(e);
          }
          *(s16x4*)&Eout[rowg * HWN + ncol0 + i * 16 + kc * 4] = pk;
        }
      }
    } else {
      // row = d (w*64+i*16+kc*4+j), col = n (f*16+r)
      bf16* vb = vt + (size_t)b * HWN * CHN;
      #pragma unroll
      for (int i = 0; i < 4; i++){
        int d0 = w * 64 + i * 16 + kc * 4;
        float4 tv4 = *(const float4*)&tvb[b * 256 + d0];
        #pragma unroll
        for (int f = 0; f < 4; f++){
          int n = ns * 512 + it * 64 + f * 16 + r;
          s16x4 pk;
          pk[0] = f2s(acc[i][f][0] + tv4.x);
          pk[1] = f2s(acc[i][f][1] + tv4.y);
          pk[2] = f2s(acc[i][f][2] + tv4.z);
          pk[3] = f2s(acc[i][f][3] + tv4.w);
          *(s16x4*)&vb[(size_t)n * 256 + d0] = pk;
        }
      }
    }

    if (it < 7){
      __syncthreads();                       // all waves done reading lX
      #pragma unroll
      for (int rep = 0; rep < 8; rep++){
        int c = t + rep * 256;
        *(int4*)&lX[c * 8] = pf[rep];
      }
      __syncthreads();
    }
  }

  if (!ISV){
    #pragma unroll
    for (int f = 0; f < 4; f++){
      float v = colp[f];
      v += __shfl_xor(v, 16); v += __shfl_xor(v, 32);
      if (lane < 16)
        atomicAdd(&sums[ws * 2048 + b * 256 + w * 64 + f * 16 + r], v);
    }
  }
}

// ---- K5: ES split-K. A=E_K(128 rows), B=E_Q(256) ----------------------------
__global__ __launch_bounds__(256, 2) void es_gemm(const bf16* __restrict__ Ek,
    const bf16* __restrict__ Eq, float* __restrict__ spart){
  __shared__ bf16 lA[2][128 * 32];
  __shared__ bf16 lB[2][256 * 32];
  int t = threadIdx.x, ch = blockIdx.x, mt = blockIdx.y, z = blockIdx.z;
  const bf16* At = Ek + (size_t)z * 256 * HWN + (size_t)(mt * 128) * HWN + ch * 512;
  const bf16* Bt = Eq + (size_t)z * 256 * HWN + ch * 512;
  f32x4 acc[4][8] = {};
  int lane = t & 63, w = t >> 6, r = lane & 15, kc = lane >> 4;
  int ng = w >> 1, cg = w & 1;

  auto stage = [&](int buf, int k0){
    #pragma unroll
    for (int rep = 0; rep < 2; rep++){
      int c = t + rep * 256; int row = c >> 2;
      int off = ((c & 3) ^ ((c >> 3) & 3)) * 8;
      gload16(At + (size_t)row * HWN + k0 + off, &lA[buf][c * 8]);
    }
    #pragma unroll
    for (int rep = 0; rep < 4; rep++){
      int c = t + rep * 256; int row = c >> 2;
      int off = ((c & 3) ^ ((c >> 3) & 3)) * 8;
      gload16(Bt + (size_t)row * HWN + k0 + off, &lB[buf][c * 8]);
    }
  };

  stage(0, 0);
  __syncthreads();
  int cur = 0;
  int slot8 = (kc ^ ((r >> 1) & 3)) * 8;
  for (int ks = 0; ks < 16; ks++){
    if (ks < 15) stage(cur ^ 1, (ks + 1) * 32);
    bf16x8 af[4], bfv[8];
    #pragma unroll
    for (int i = 0; i < 4; i++)
      af[i] = *(const bf16x8*)&lA[cur][(ng * 64 + i * 16 + r) * 32 + slot8];
    #pragma unroll
    for (int f = 0; f < 8; f++)
      bfv[f] = *(const bf16x8*)&lB[cur][(cg * 128 + f * 16 + r) * 32 + slot8];
    #pragma unroll
    for (int i = 0; i < 4; i++)
      #pragma unroll
      for (int f = 0; f < 8; f++)
        acc[i][f] = __builtin_amdgcn_mfma_f32_16x16x32_bf16(af[i], bfv[f], acc[i][f], 0, 0, 0);
    __syncthreads();
    cur ^= 1;
  }

  float* sp = spart + ((size_t)(z * ESCH + ch) << 16);
  #pragma unroll
  for (int f = 0; f < 8; f++){
    int q = cg * 128 + f * 16 + r;
    #pragma unroll
    for (int i = 0; i < 4; i++){
      int k0i = mt * 128 + ng * 64 + i * 16 + kc * 4;
      *(f32x4*)&sp[q * 256 + k0i] = acc[i][f];
    }
  }
}

// ---- K6a: reduce split-K partials of ES --------------------------------------
__global__ void reduce_S(const float* __restrict__ sp, float* __restrict__ S){
  size_t i = (size_t)blockIdx.x * 256 + threadIdx.x;
  size_t b = i >> 16, cd = i & 65535;
  float s = 0.f;
  #pragma unroll
  for (int ch = 0; ch < ESCH; ch++) s += sp[((b * ESCH + ch) << 16) + cd];
  S[i] = s;
}

// ---- K6b: M = colscale(Wo,1/(16 sq)) * S, then /sk -> bf16 -------------------
__global__ __launch_bounds__(256) void make_M(const float* __restrict__ Wo,
    const float* __restrict__ S, const float* __restrict__ sq,
    const float* __restrict__ sk, bf16* __restrict__ Mb){
  int b = blockIdx.y, o0 = blockIdx.x * 16;
  __shared__ float wo_s[16][256];
  __shared__ float invsk[256];
  int t = threadIdx.x;
  #pragma unroll
  for (int i = 0; i < 16; i++){
    int idx = i * 256 + t, ol = idx >> 8, c = idx & 255;
    wo_s[ol][c] = Wo[(size_t)(o0 + ol) * 256 + c] * 0.0625f / sq[b * 256 + c];
  }
  invsk[t] = 1.f / sk[b * 256 + t];
  __syncthreads();
  int ol = t >> 4, d0 = (t & 15) * 16;
  const float* Sb = S + ((size_t)b << 16);
  float acc[16] = {};
  for (int c = 0; c < 256; c++){
    float w = wo_s[ol][c];
    const float4* Sr = (const float4*)(Sb + (c << 8) + d0);
    #pragma unroll
    for (int q4 = 0; q4 < 4; q4++){
      float4 sv = Sr[q4];
      acc[q4*4+0] += w * sv.x; acc[q4*4+1] += w * sv.y;
      acc[q4*4+2] += w * sv.z; acc[q4*4+3] += w * sv.w;
    }
  }
  bf16* Mo = Mb + ((size_t)b << 16) + (size_t)(o0 + ol) * 256 + d0;
  #pragma unroll
  for (int j = 0; j < 16; j++) Mo[j] = __float2bfloat16(acc[j] * invsk[d0 + j]);
}

// ---- K7: out[o][n] = M*V^T + bo. A=vt(128 n), B=M(256 o), f32 float4 stores --
__global__ __launch_bounds__(256, 2) void out_gemm(const bf16* __restrict__ vt,
    const bf16* __restrict__ Mb, const float* __restrict__ bo,
    float* __restrict__ out){
  __shared__ bf16 lA[2][128 * 32];
  __shared__ bf16 lB[2][256 * 32];
  int t = threadIdx.x, nt = blockIdx.x, z = blockIdx.y;
  const bf16* At = vt + (size_t)z * HWN * CHN + (size_t)(nt * 128) * CHN;
  const bf16* Bt = Mb + (size_t)z * 65536;
  f32x4 acc[4][8] = {};
  int lane = t & 63, w = t >> 6, r = lane & 15, kc = lane >> 4;
  int ng = w >> 1, cg = w & 1;

  auto stage = [&](int buf, int k0){
    #pragma unroll
    for (int rep = 0; rep < 2; rep++){
      int c = t + rep * 256; int row = c >> 2;
      int off = ((c & 3) ^ ((c >> 3) & 3)) * 8;
      gload16(At + (size_t)row * 256 + k0 + off, &lA[buf][c * 8]);
    }
    #pragma unroll
    for (int rep = 0; rep < 4; rep++){
      int c = t + rep * 256; int row = c >> 2;
      int off = ((c & 3) ^ ((c >> 3) & 3)) * 8;
      gload16(Bt + (size_t)row * 256 + k0 + off, &lB[buf][c * 8]);
    }
  };

  stage(0, 0);
  __syncthreads();
  int cur = 0;
  int slot8 = (kc ^ ((r >> 1) & 3)) * 8;
  for (int ks = 0; ks < 8; ks++){
    if (ks < 7) stage(cur ^ 1, (ks + 1) * 32);
    bf16x8 af[4], bfv[8];
    #pragma unroll
    for (int i = 0; i < 4; i++)
      af[i] = *(const bf16x8*)&lA[cur][(ng * 64 + i * 16 + r) * 32 + slot8];
    #pragma unroll
    for (int f = 0; f < 8; f++)
      bfv[f] = *(const bf16x8*)&lB[cur][(cg * 128 + f * 16 + r) * 32 + slot8];
    #pragma unroll
    for (int i = 0; i < 4; i++)
      #pragma unroll
      for (int f = 0; f < 8; f++)
        acc[i][f] = __builtin_amdgcn_mfma_f32_16x16x32_bf16(af[i], bfv[f], acc[i][f], 0, 0, 0);
    __syncthreads();
    cur ^= 1;
  }

  float* ob = out + (size_t)z * CHN * HWN;
  #pragma unroll
  for (int f = 0; f < 8; f++){
    int o = cg * 128 + f * 16 + r;
    float bb = bo[o];
    #pragma unroll
    for (int i = 0; i < 4; i++){
      int n0 = nt * 128 + ng * 64 + i * 16 + kc * 4;
      float4 st = { acc[i][f][0] + bb, acc[i][f][1] + bb,
                    acc[i][f][2] + bb, acc[i][f][3] + bb };
      *(float4*)&ob[(size_t)o * HWN + n0] = st;
    }
  }
}

// ------------------------------------------------------------------------------
extern "C" void kernel_launch(void* const* d_in, const int* in_sizes, int n_in,
                              void* d_out, int out_size, void* d_ws, size_t ws_size,
                              hipStream_t stream){
  const float* x     = (const float*)d_in[0];
  const float* gamma = (const float*)d_in[1];
  const float* beta  = (const float*)d_in[2];
  const float* Wq    = (const float*)d_in[3];
  const float* Wk    = (const float*)d_in[5];
  const float* Wv    = (const float*)d_in[7];
  const float* bv    = (const float*)d_in[8];
  const float* Wo    = (const float*)d_in[9];
  const float* bo    = (const float*)d_in[10];
  // bq/bk and the GN-shift term are per-row constants in Q/K -> cancel in softmax.

  char* ws = (char*)d_ws;
  bf16*  xt    = (bf16*) (ws + 0);            // 64 MiB x^T bf16 (dead after qkv)
  float* spart = (float*)(ws + 0);            // 64 MiB ES partials (overlays xt)
  bf16*  vt    = (bf16*) (ws + 67108864);     // 64 MiB V^T [b][n][d]
  bf16*  wbp   = (bf16*) (ws + 134217728);    // 3 MiB  W'[3][8][256][256] bf16
  float* S     = (float*)(ws + 137363456);    // 2 MiB  ES [b][c][d]
  bf16*  Mb    = (bf16*) (ws + 139460608);    // 1 MiB  M bf16 [b][o][d]
  float* sums  = (float*)(ws + 140509184);    // 16 KiB sq[2048], sk[2048]
  float* pst   = (float*)(ws + 140525568);    // 2 KiB  GN partial s/ss per (b,g)
  float* tvb   = (float*)(ws + 140527616);    // 8 KiB  V shift vec per batch

  bf16* Qb = (bf16*)d_out;                    // E_Q rows 0..2047
  bf16* Kb = Qb + (size_t)2048 * HWN;         // E_K rows 2048..4095

  hipMemsetAsync(sums, 0, 4096 * sizeof(float), stream);
  hipMemsetAsync(pst,  0,  512 * sizeof(float), stream);

  // single pass over x: stats + raw bf16 transpose
  xstats_t<<<dim3(256, 8), dim3(256), 0, stream>>>(x, xt, pst);
  // per-batch folded weights + V shift vector
  wprep<<<dim3(3, 8), dim3(256), 0, stream>>>(Wq, Wk, Wv, gamma, beta, bv, pst, wbp, tvb);
  // E_Q/E_K = exp(W' x) + col sums; V^T = W'v x + tvb
  qkv_gemm<0><<<dim3(32, 8, 2), dim3(256), 0, stream>>>(wbp, xt, nullptr, Qb, nullptr, sums);
  qkv_gemm<1><<<dim3(32, 8, 1), dim3(256), 0, stream>>>(wbp, xt, tvb, nullptr, vt, nullptr);
  // ES split-K partials (spart overlays dead xt)
  es_gemm<<<dim3(ESCH, 2, 8), dim3(256), 0, stream>>>(Kb, Qb, spart);
  reduce_S<<<dim3(2048), dim3(256), 0, stream>>>(spart, S);
  // M = (Wo . diag(1/(16 sq))) * S * diag(1/sk) -> bf16
  make_M<<<dim3(16, 8), dim3(256), 0, stream>>>(Wo, S, sums, sums + 2048, Mb);
  // out = M * V + bo -> f32 (overwrites E scratch in d_out)
  out_gemm<<<dim3(128, 8), dim3(256), 0, stream>>>(vt, Mb, bo, (float*)d_out);
}

// Round 7
// 400.922 us; speedup vs baseline: 1.3429x; 1.3429x over previous
//
#include <hip/hip_runtime.h>
#include <hip/hip_bf16.h>

#define BATCH 8
#define CHN 256
#define HWN 16384
#define EPSV 1e-6f
#define ESCH 32

typedef __attribute__((ext_vector_type(8))) short bf16x8;
typedef __attribute__((ext_vector_type(4))) short s16x4;
typedef __attribute__((ext_vector_type(4))) float f32x4;
typedef __hip_bfloat16 bf16;

__device__ __forceinline__ short f2s(float f){
  union { bf16 h; short s; } u; u.h = __float2bfloat16(f); return u.s;
}
__device__ __forceinline__ void gload16(const bf16* g, bf16* l){
  __builtin_amdgcn_global_load_lds((const __attribute__((address_space(1))) void*)g,
                                   (__attribute__((address_space(3))) void*)l, 16, 0, 0);
}

// ---- K1: read x once: GN partial stats + raw transpose x^T -> bf16 ----------
__global__ __launch_bounds__(256) void xstats_t(const float* __restrict__ x,
    bf16* __restrict__ xt, float* __restrict__ pst){
  int b = blockIdx.y, n0 = blockIdx.x * 64;
  __shared__ bf16 tile[256][70];
  __shared__ float sg[32], ssg[32];
  int t = threadIdx.x;
  if (t < 32){ sg[t] = 0.f; ssg[t] = 0.f; }
  __syncthreads();
  const float* xb = x + (size_t)b * CHN * HWN;
  #pragma unroll 4
  for (int i = 0; i < 16; i++){
    int c = i * 16 + (t >> 4);
    int nf = (t & 15) * 4;
    float4 v = *(const float4*)(xb + (size_t)c * HWN + n0 + nf);
    tile[c][nf + 0] = __float2bfloat16(v.x);
    tile[c][nf + 1] = __float2bfloat16(v.y);
    tile[c][nf + 2] = __float2bfloat16(v.z);
    tile[c][nf + 3] = __float2bfloat16(v.w);
    float s  = v.x + v.y + v.z + v.w;
    float ss = v.x*v.x + v.y*v.y + v.z*v.z + v.w*v.w;
    s  += __shfl_xor(s, 1);  s  += __shfl_xor(s, 2);
    s  += __shfl_xor(s, 4);  s  += __shfl_xor(s, 8);
    ss += __shfl_xor(ss, 1); ss += __shfl_xor(ss, 2);
    ss += __shfl_xor(ss, 4); ss += __shfl_xor(ss, 8);
    if ((t & 15) == 0){ atomicAdd(&sg[c >> 3], s); atomicAdd(&ssg[c >> 3], ss); }
  }
  __syncthreads();
  bf16* o = xt + (size_t)b * HWN * CHN;
  #pragma unroll 4
  for (int j = 0; j < 64; j++)
    o[(size_t)(n0 + j) * CHN + t] = tile[t][j];
  if (t < 32){
    atomicAdd(&pst[(b * 32 + t) * 2],     sg[t]);
    atomicAdd(&pst[(b * 32 + t) * 2 + 1], ssg[t]);
  }
}

// ---- K2: per-batch folded weights W'[b] = W.diag(a_b) bf16; V shift vec -----
// grid (3, 8, 16): 16-row tile per block; coalesced rows, parallel reduction.
__global__ __launch_bounds__(256) void wprep(const float* __restrict__ Wq,
    const float* __restrict__ Wk, const float* __restrict__ Wv,
    const float* __restrict__ gamma, const float* __restrict__ beta,
    const float* __restrict__ bv, const float* __restrict__ pst,
    bf16* __restrict__ wbp, float* __restrict__ tvb){
  int w = blockIdx.x, b = blockIdx.y, rt = blockIdx.z, t = threadIdx.x;
  const float* W = (w == 0) ? Wq : ((w == 1) ? Wk : Wv);
  __shared__ float a_s[256], sh_s[256];
  __shared__ float racc[16];
  {
    int bg = b * 32 + (t >> 3);
    float m   = pst[bg * 2] * (1.f / 131072.f);
    float var = pst[bg * 2 + 1] * (1.f / 131072.f) - m * m;
    float r = rsqrtf(var + EPSV);
    float a = r * gamma[t];
    a_s[t] = a;
    sh_s[t] = beta[t] - m * a;
  }
  if (t < 16) racc[t] = 0.f;
  __syncthreads();
  float mya = a_s[t], mysh = sh_s[t];
  int lane = t & 63;
  bf16* wo = wbp + ((size_t)(w * 8 + b) << 16);
  #pragma unroll
  for (int jj = 0; jj < 16; jj++){
    int j = rt * 16 + jj;
    float wv_ = W[j * 256 + t];
    wo[j * 256 + t] = __float2bfloat16(wv_ * mya);
    if (w == 2){
      float p = wv_ * mysh;
      p += __shfl_xor(p, 1);  p += __shfl_xor(p, 2);  p += __shfl_xor(p, 4);
      p += __shfl_xor(p, 8);  p += __shfl_xor(p, 16); p += __shfl_xor(p, 32);
      if (lane == 0) atomicAdd(&racc[jj], p);
    }
  }
  if (w == 2){
    __syncthreads();
    if (t < 16) tvb[b * 256 + rt * 16 + t] = racc[t] + bv[rt * 16 + t];
  }
}

// ---- K3: weights-resident QKV projection ------------------------------------
// LDS: full W' chunk 256x256 (128 KB, staged once) + xt tile 64x256 (32 KB).
// ISV=0: grid(ns,b,ws 0..1): E=exp(W'x) -> Eout rows ws*2048+b*256+.., col-sums.
// ISV=1: grid(ns,b,1):       V^T[b][n][d] = W'v x + tvb.
template<int ISV>
__global__ __launch_bounds__(256, 1) void qkv_gemm(const bf16* __restrict__ wbp,
    const bf16* __restrict__ xt, const float* __restrict__ tvb,
    bf16* __restrict__ Eout, bf16* __restrict__ vt, float* __restrict__ sums){
  __shared__ bf16 lW[256 * 256];             // 128 KB
  __shared__ bf16 lX[64 * 256];              // 32 KB
  int t = threadIdx.x, ns = blockIdx.x, b = blockIdx.y, ws = blockIdx.z;
  int wsel = ISV ? 2 : ws;
  const bf16* Wsrc = wbp + ((size_t)(wsel * 8 + b) << 16);
  const bf16* Xb = xt + (size_t)b * HWN * CHN + (size_t)(ns * 512) * CHN;
  int lane = t & 63, w = t >> 6, r = lane & 15, kc = lane >> 4;
  int key_r = (r >> 1) & 3;

  // stage W' once (swizzled source -> linear LDS dest)
  #pragma unroll
  for (int rep = 0; rep < 32; rep++){
    int c = t + rep * 256; int row = c >> 5, q = c & 31;
    int kb = q >> 2, key = (row >> 1) & 3;
    gload16(Wsrc + row * 256 + kb * 32 + (((q & 3) ^ key) << 3), &lW[c * 8]);
  }
  // stage first xt tile
  #pragma unroll
  for (int rep = 0; rep < 8; rep++){
    int c = t + rep * 256; int row = c >> 5, q = c & 31;
    int kb = q >> 2, key = (row >> 1) & 3;
    gload16(Xb + (size_t)row * 256 + kb * 32 + (((q & 3) ^ key) << 3), &lX[c * 8]);
  }
  __syncthreads();

  const bf16* Ab = ISV ? &lW[(w * 64) * 256] : &lX[0];
  const bf16* Bb = ISV ? &lX[0] : &lW[(w * 64) * 256];
  float colp[4] = {0.f, 0.f, 0.f, 0.f};

  for (int it = 0; it < 8; it++){
    // T14: prefetch next tile to regs (hides under k-loop + epilogue)
    int4 pf[8];
    if (it < 7){
      const bf16* Xn = Xb + (size_t)((it + 1) * 64) * CHN;
      #pragma unroll
      for (int rep = 0; rep < 8; rep++){
        int c = t + rep * 256; int row = c >> 5, q = c & 31;
        int kb = q >> 2, key = (row >> 1) & 3;
        pf[rep] = *(const int4*)(Xn + (size_t)row * 256 + kb * 32 + (((q & 3) ^ key) << 3));
      }
    }
    f32x4 acc[4][4] = {};
    #pragma unroll
    for (int ks = 0; ks < 8; ks++){
      bf16x8 af[4], bfv[4];
      int slot = ks * 32 + ((kc ^ key_r) << 3);
      #pragma unroll
      for (int i = 0; i < 4; i++){
        af[i]  = *(const bf16x8*)&Ab[(i * 16 + r) * 256 + slot];
        bfv[i] = *(const bf16x8*)&Bb[(i * 16 + r) * 256 + slot];
      }
      #pragma unroll
      for (int i = 0; i < 4; i++)
        #pragma unroll
        for (int f = 0; f < 4; f++)
          acc[i][f] = __builtin_amdgcn_mfma_f32_16x16x32_bf16(af[i], bfv[f], acc[i][f], 0, 0, 0);
    }

    // epilogue (registers -> global; D row = A-side, col = B-side)
    if (!ISV){
      // row = n (i*16+kc*4+j), col = wrow (f*16+r)
      int ncol0 = ns * 512 + it * 64;
      #pragma unroll
      for (int f = 0; f < 4; f++){
        size_t rowg = (size_t)(ws * 2048 + b * 256 + w * 64 + f * 16 + r);
        #pragma unroll
        for (int i = 0; i < 4; i++){
          s16x4 pk;
          #pragma unroll
          for (int j = 0; j < 4; j++){
            float e = __expf(acc[i][f][j]);  // |q| small: no max-sub needed
            colp[f] += e;
            pk[j] = f2s(e);
          }
          *(s16x4*)&Eout[rowg * HWN + ncol0 + i * 16 + kc * 4] = pk;
        }
      }
    } else {
      // row = d (w*64+i*16+kc*4+j), col = n (f*16+r)
      bf16* vb = vt + (size_t)b * HWN * CHN;
      #pragma unroll
      for (int i = 0; i < 4; i++){
        int d0 = w * 64 + i * 16 + kc * 4;
        float4 tv4 = *(const float4*)&tvb[b * 256 + d0];
        #pragma unroll
        for (int f = 0; f < 4; f++){
          int n = ns * 512 + it * 64 + f * 16 + r;
          s16x4 pk;
          pk[0] = f2s(acc[i][f][0] + tv4.x);
          pk[1] = f2s(acc[i][f][1] + tv4.y);
          pk[2] = f2s(acc[i][f][2] + tv4.z);
          pk[3] = f2s(acc[i][f][3] + tv4.w);
          *(s16x4*)&vb[(size_t)n * 256 + d0] = pk;
        }
      }
    }

    if (it < 7){
      __syncthreads();                       // all waves done reading lX
      #pragma unroll
      for (int rep = 0; rep < 8; rep++){
        int c = t + rep * 256;
        *(int4*)&lX[c * 8] = pf[rep];
      }
      __syncthreads();
    }
  }

  if (!ISV){
    #pragma unroll
    for (int f = 0; f < 4; f++){
      float v = colp[f];
      v += __shfl_xor(v, 16); v += __shfl_xor(v, 32);
      if (lane < 16)
        atomicAdd(&sums[ws * 2048 + b * 256 + w * 64 + f * 16 + r], v);
    }
  }
}

// ---- K5: ES split-K. A=E_K(128 rows), B=E_Q(256) ----------------------------
__global__ __launch_bounds__(256, 2) void es_gemm(const bf16* __restrict__ Ek,
    const bf16* __restrict__ Eq, float* __restrict__ spart){
  __shared__ bf16 lA[2][128 * 32];
  __shared__ bf16 lB[2][256 * 32];
  int t = threadIdx.x, ch = blockIdx.x, mt = blockIdx.y, z = blockIdx.z;
  const bf16* At = Ek + (size_t)z * 256 * HWN + (size_t)(mt * 128) * HWN + ch * 512;
  const bf16* Bt = Eq + (size_t)z * 256 * HWN + ch * 512;
  f32x4 acc[4][8] = {};
  int lane = t & 63, w = t >> 6, r = lane & 15, kc = lane >> 4;
  int ng = w >> 1, cg = w & 1;

  auto stage = [&](int buf, int k0){
    #pragma unroll
    for (int rep = 0; rep < 2; rep++){
      int c = t + rep * 256; int row = c >> 2;
      int off = ((c & 3) ^ ((c >> 3) & 3)) * 8;
      gload16(At + (size_t)row * HWN + k0 + off, &lA[buf][c * 8]);
    }
    #pragma unroll
    for (int rep = 0; rep < 4; rep++){
      int c = t + rep * 256; int row = c >> 2;
      int off = ((c & 3) ^ ((c >> 3) & 3)) * 8;
      gload16(Bt + (size_t)row * HWN + k0 + off, &lB[buf][c * 8]);
    }
  };

  stage(0, 0);
  __syncthreads();
  int cur = 0;
  int slot8 = (kc ^ ((r >> 1) & 3)) * 8;
  for (int ks = 0; ks < 16; ks++){
    if (ks < 15) stage(cur ^ 1, (ks + 1) * 32);
    bf16x8 af[4], bfv[8];
    #pragma unroll
    for (int i = 0; i < 4; i++)
      af[i] = *(const bf16x8*)&lA[cur][(ng * 64 + i * 16 + r) * 32 + slot8];
    #pragma unroll
    for (int f = 0; f < 8; f++)
      bfv[f] = *(const bf16x8*)&lB[cur][(cg * 128 + f * 16 + r) * 32 + slot8];
    #pragma unroll
    for (int i = 0; i < 4; i++)
      #pragma unroll
      for (int f = 0; f < 8; f++)
        acc[i][f] = __builtin_amdgcn_mfma_f32_16x16x32_bf16(af[i], bfv[f], acc[i][f], 0, 0, 0);
    __syncthreads();
    cur ^= 1;
  }

  float* sp = spart + ((size_t)(z * ESCH + ch) << 16);
  #pragma unroll
  for (int f = 0; f < 8; f++){
    int q = cg * 128 + f * 16 + r;
    #pragma unroll
    for (int i = 0; i < 4; i++){
      int k0i = mt * 128 + ng * 64 + i * 16 + kc * 4;
      *(f32x4*)&sp[q * 256 + k0i] = acc[i][f];
    }
  }
}

// ---- K6a: reduce split-K partials of ES --------------------------------------
__global__ void reduce_S(const float* __restrict__ sp, float* __restrict__ S){
  size_t i = (size_t)blockIdx.x * 256 + threadIdx.x;
  size_t b = i >> 16, cd = i & 65535;
  float s = 0.f;
  #pragma unroll
  for (int ch = 0; ch < ESCH; ch++) s += sp[((b * ESCH + ch) << 16) + cd];
  S[i] = s;
}

// ---- K6b: M = colscale(Wo,1/(16 sq)) * S, then /sk -> bf16 -------------------
__global__ __launch_bounds__(256) void make_M(const float* __restrict__ Wo,
    const float* __restrict__ S, const float* __restrict__ sq,
    const float* __restrict__ sk, bf16* __restrict__ Mb){
  int b = blockIdx.y, o0 = blockIdx.x * 16;
  __shared__ float wo_s[16][256];
  __shared__ float invsk[256];
  int t = threadIdx.x;
  #pragma unroll
  for (int i = 0; i < 16; i++){
    int idx = i * 256 + t, ol = idx >> 8, c = idx & 255;
    wo_s[ol][c] = Wo[(size_t)(o0 + ol) * 256 + c] * 0.0625f / sq[b * 256 + c];
  }
  invsk[t] = 1.f / sk[b * 256 + t];
  __syncthreads();
  int ol = t >> 4, d0 = (t & 15) * 16;
  const float* Sb = S + ((size_t)b << 16);
  float acc[16] = {};
  for (int c = 0; c < 256; c++){
    float w = wo_s[ol][c];
    const float4* Sr = (const float4*)(Sb + (c << 8) + d0);
    #pragma unroll
    for (int q4 = 0; q4 < 4; q4++){
      float4 sv = Sr[q4];
      acc[q4*4+0] += w * sv.x; acc[q4*4+1] += w * sv.y;
      acc[q4*4+2] += w * sv.z; acc[q4*4+3] += w * sv.w;
    }
  }
  bf16* Mo = Mb + ((size_t)b << 16) + (size_t)(o0 + ol) * 256 + d0;
  #pragma unroll
  for (int j = 0; j < 16; j++) Mo[j] = __float2bfloat16(acc[j] * invsk[d0 + j]);
}

// ---- K7: out[o][n] = M*V^T + bo. A=vt(128 n), B=M(256 o), f32 float4 stores --
__global__ __launch_bounds__(256, 2) void out_gemm(const bf16* __restrict__ vt,
    const bf16* __restrict__ Mb, const float* __restrict__ bo,
    float* __restrict__ out){
  __shared__ bf16 lA[2][128 * 32];
  __shared__ bf16 lB[2][256 * 32];
  int t = threadIdx.x, nt = blockIdx.x, z = blockIdx.y;
  const bf16* At = vt + (size_t)z * HWN * CHN + (size_t)(nt * 128) * CHN;
  const bf16* Bt = Mb + (size_t)z * 65536;
  f32x4 acc[4][8] = {};
  int lane = t & 63, w = t >> 6, r = lane & 15, kc = lane >> 4;
  int ng = w >> 1, cg = w & 1;

  auto stage = [&](int buf, int k0){
    #pragma unroll
    for (int rep = 0; rep < 2; rep++){
      int c = t + rep * 256; int row = c >> 2;
      int off = ((c & 3) ^ ((c >> 3) & 3)) * 8;
      gload16(At + (size_t)row * 256 + k0 + off, &lA[buf][c * 8]);
    }
    #pragma unroll
    for (int rep = 0; rep < 4; rep++){
      int c = t + rep * 256; int row = c >> 2;
      int off = ((c & 3) ^ ((c >> 3) & 3)) * 8;
      gload16(Bt + (size_t)row * 256 + k0 + off, &lB[buf][c * 8]);
    }
  };

  stage(0, 0);
  __syncthreads();
  int cur = 0;
  int slot8 = (kc ^ ((r >> 1) & 3)) * 8;
  for (int ks = 0; ks < 8; ks++){
    if (ks < 7) stage(cur ^ 1, (ks + 1) * 32);
    bf16x8 af[4], bfv[8];
    #pragma unroll
    for (int i = 0; i < 4; i++)
      af[i] = *(const bf16x8*)&lA[cur][(ng * 64 + i * 16 + r) * 32 + slot8];
    #pragma unroll
    for (int f = 0; f < 8; f++)
      bfv[f] = *(const bf16x8*)&lB[cur][(cg * 128 + f * 16 + r) * 32 + slot8];
    #pragma unroll
    for (int i = 0; i < 4; i++)
      #pragma unroll
      for (int f = 0; f < 8; f++)
        acc[i][f] = __builtin_amdgcn_mfma_f32_16x16x32_bf16(af[i], bfv[f], acc[i][f], 0, 0, 0);
    __syncthreads();
    cur ^= 1;
  }

  float* ob = out + (size_t)z * CHN * HWN;
  #pragma unroll
  for (int f = 0; f < 8; f++){
    int o = cg * 128 + f * 16 + r;
    float bb = bo[o];
    #pragma unroll
    for (int i = 0; i < 4; i++){
      int n0 = nt * 128 + ng * 64 + i * 16 + kc * 4;
      float4 st = { acc[i][f][0] + bb, acc[i][f][1] + bb,
                    acc[i][f][2] + bb, acc[i][f][3] + bb };
      *(float4*)&ob[(size_t)o * HWN + n0] = st;
    }
  }
}

// ------------------------------------------------------------------------------
extern "C" void kernel_launch(void* const* d_in, const int* in_sizes, int n_in,
                              void* d_out, int out_size, void* d_ws, size_t ws_size,
                              hipStream_t stream){
  const float* x     = (const float*)d_in[0];
  const float* gamma = (const float*)d_in[1];
  const float* beta  = (const float*)d_in[2];
  const float* Wq    = (const float*)d_in[3];
  const float* Wk    = (const float*)d_in[5];
  const float* Wv    = (const float*)d_in[7];
  const float* bv    = (const float*)d_in[8];
  const float* Wo    = (const float*)d_in[9];
  const float* bo    = (const float*)d_in[10];
  // bq/bk and the GN-shift term are per-row constants in Q/K -> cancel in softmax.

  char* ws = (char*)d_ws;
  bf16*  xt    = (bf16*) (ws + 0);            // 64 MiB x^T bf16 (dead after qkv)
  float* spart = (float*)(ws + 0);            // 64 MiB ES partials (overlays xt)
  bf16*  vt    = (bf16*) (ws + 67108864);     // 64 MiB V^T [b][n][d]
  bf16*  wbp   = (bf16*) (ws + 134217728);    // 3 MiB  W'[3][8][256][256] bf16
  float* S     = (float*)(ws + 137363456);    // 2 MiB  ES [b][c][d]
  bf16*  Mb    = (bf16*) (ws + 139460608);    // 1 MiB  M bf16 [b][o][d]
  float* sums  = (float*)(ws + 140509184);    // 16 KiB sq[2048], sk[2048]
  float* pst   = (float*)(ws + 140525568);    // 2 KiB  GN partial s/ss per (b,g)
  float* tvb   = (float*)(ws + 140527616);    // 8 KiB  V shift vec per batch

  bf16* Qb = (bf16*)d_out;                    // E_Q rows 0..2047
  bf16* Kb = Qb + (size_t)2048 * HWN;         // E_K rows 2048..4095

  hipMemsetAsync(sums, 0, 4096 * sizeof(float), stream);
  hipMemsetAsync(pst,  0,  512 * sizeof(float), stream);

  // single pass over x: stats + raw bf16 transpose
  xstats_t<<<dim3(256, 8), dim3(256), 0, stream>>>(x, xt, pst);
  // per-batch folded weights + V shift vector (parallel: 384 blocks)
  wprep<<<dim3(3, 8, 16), dim3(256), 0, stream>>>(Wq, Wk, Wv, gamma, beta, bv, pst, wbp, tvb);
  // E_Q/E_K = exp(W' x) + col sums; V^T = W'v x + tvb
  qkv_gemm<0><<<dim3(32, 8, 2), dim3(256), 0, stream>>>(wbp, xt, nullptr, Qb, nullptr, sums);
  qkv_gemm<1><<<dim3(32, 8, 1), dim3(256), 0, stream>>>(wbp, xt, tvb, nullptr, vt, nullptr);
  // ES split-K partials (spart overlays dead xt)
  es_gemm<<<dim3(ESCH, 2, 8), dim3(256), 0, stream>>>(Kb, Qb, spart);
  reduce_S<<<dim3(2048), dim3(256), 0, stream>>>(spart, S);
  // M = (Wo . diag(1/(16 sq))) * S * diag(1/sk) -> bf16
  make_M<<<dim3(16, 8), dim3(256), 0, stream>>>(Wo, S, sums, sums + 2048, Mb);
  // out = M * V + bo -> f32 (overwrites E scratch in d_out)
  out_gemm<<<dim3(128, 8), dim3(256), 0, stream>>>(vt, Mb, bo, (float*)d_out);
}